// Round 8
// baseline (561.233 us; speedup 1.0000x reference)
//
#include <hip/hip_runtime.h>
#include <hip/hip_bf16.h>

// GCN link-prediction net, algebraically collapsed + dinv pre-scaling:
//   H[r]  = bf16( (x @ W1)[r] * dinv[r] )            (bf16 MFMA, fp32 accum)
//   agg1[c] = dinv[c] * ( H[c] + sum_{e->c} H[src] ) (unweighted sum)
//   g[c]  = relu(agg1[c] + b1) . (W2 @ score_w);  gs[c] = g[c]*dinv[c]
//   hw[c] = dinv[c] * ( gs[c] + sum gs[src] )
//   out[e] = relu(hw[src]-hw[dst] + sb); loss = mean(hw[src]-hw[dst])
// CSR built via two-phase bucket sort with LDS write-combining (R7: 906->555us).
// R8: agg1 latency-bound (845MB L3-resident gathers at ~5.6TB/s-eq) -> 8 gathers
// in flight per wave (was 4); agg_s 16-deep; w2v merged into wt prep.

#define F_IN 512
#define F_H  128
#define F_C  64

#define NBMAX 392          // buckets of 256 targets, N=100000 -> 391
#define MAXB  14336        // padded per-bucket capacity (mean 12.9k + >10 sigma)
#define SENT  0xFFFFFFFFu

typedef __attribute__((ext_vector_type(8))) short short8;
typedef __attribute__((ext_vector_type(4))) float f32x4;

__device__ __forceinline__ ushort f2bf(float f) {
    uint u = __float_as_uint(f);
    uint r = (u + 0x7fffu + ((u >> 16) & 1u)) >> 16;   // RNE
    return (ushort)r;
}
__device__ __forceinline__ float bflo(uint v) { return __uint_as_float(v << 16); }
__device__ __forceinline__ float bfhi(uint v) { return __uint_as_float(v & 0xffff0000u); }

__device__ __forceinline__ void gload_lds16(const void* g, void* l) {
    __builtin_amdgcn_global_load_lds(
        (const __attribute__((address_space(1))) void*)g,
        (__attribute__((address_space(3))) void*)l, 16, 0, 0);
}

// ---------------- phase A: bucket edges with line-aligned flushes ----------------
// pack = (local_target(8b) << 17) | src(17b). Per tile of 4096 edges, entries
// stage in LDS; flusher thread per bucket reserves roundup16 slots (keeps 16B
// alignment) and writes full uint4 lines with sentinel padding.

__global__ __launch_bounds__(1024) void bucketA_kernel(
        const int* __restrict__ ei, int E, int ntiles, int NB,
        uint* __restrict__ bdata, int* __restrict__ bcnt, int* __restrict__ rcnt) {
    __shared__ int  hist[512];
    __shared__ uint stage[NBMAX * 32];
    int tid = threadIdx.x;
    if (tid < NB) hist[tid] = 0;
    __syncthreads();
    for (int tb = blockIdx.x; tb < ntiles; tb += gridDim.x) {
        int e0 = tb * 4096;
        #pragma unroll
        for (int j = 0; j < 4; ++j) {
            int e = e0 + j * 1024 + tid;
            if (e < E) {
                int r = ei[e];              // source
                int c = ei[E + e];          // target
                int b = c >> 8;
                uint pk = ((uint)(c & 255) << 17) | (uint)r;
                int pos = atomicAdd(&hist[b], 1);
                if (pos < 32) {
                    stage[b * 32 + pos] = pk;
                } else {                    // overflow (P ~ 1e-5): padded line
                    int gp = atomicAdd(&bcnt[b], 16);
                    atomicAdd(&rcnt[b], 1);
                    uint4* dst = (uint4*)(bdata + (size_t)b * MAXB + gp);
                    uint4 v0 = {pk, SENT, SENT, SENT};
                    uint4 vs = {SENT, SENT, SENT, SENT};
                    dst[0] = v0; dst[1] = vs; dst[2] = vs; dst[3] = vs;
                }
            }
        }
        __syncthreads();
        if (tid < NB) {
            int h = hist[tid];
            int st = h < 32 ? h : 32;
            if (st > 0) {
                int pads = (st + 15) & ~15;
                int gp = atomicAdd(&bcnt[tid], pads);
                atomicAdd(&rcnt[tid], st);
                uint* dst = bdata + (size_t)tid * MAXB + gp;
                for (int k = 0; k < pads; k += 4) {
                    uint4 v;
                    v.x = (k + 0 < st) ? stage[tid * 32 + k + 0] : SENT;
                    v.y = (k + 1 < st) ? stage[tid * 32 + k + 1] : SENT;
                    v.z = (k + 2 < st) ? stage[tid * 32 + k + 2] : SENT;
                    v.w = (k + 3 < st) ? stage[tid * 32 + k + 3] : SENT;
                    *(uint4*)(dst + k) = v;
                }
            }
            hist[tid] = 0;
        }
        __syncthreads();
    }
}

// exclusive scan of real bucket counts -> bbase[0..NB], bbase[NB]=E
__global__ __launch_bounds__(512) void bbase_kernel(const int* __restrict__ rcnt,
                                                    int* __restrict__ bbase,
                                                    int NB, int E) {
    __shared__ int sm[512];
    int t = threadIdx.x;
    int v = (t < NB) ? rcnt[t] : 0;
    sm[t] = v;
    __syncthreads();
    for (int d = 1; d < 512; d <<= 1) {
        int u = (t >= d) ? sm[t - d] : 0;
        __syncthreads();
        sm[t] += u;
        __syncthreads();
    }
    if (t < NB) bbase[t] = sm[t] - v;
    if (t == 0) bbase[NB] = E;
}

// ---------------- phase B: per-bucket counting sort -> csr, offs, dinv ----------------

__global__ __launch_bounds__(1024) void bucketB_kernel(
        const uint* __restrict__ bdata, const int* __restrict__ bcnt,
        const int* __restrict__ bbase, int* __restrict__ csr,
        int* __restrict__ offs, float* __restrict__ dinv, int N, int E) {
    __shared__ int lcnt[256], lincl[256], lcur[256];
    int b = blockIdx.x, tid = threadIdx.x;
    int t0 = b << 8;
    int nt = N - t0; if (nt > 256) nt = 256;
    int ext = bcnt[b];
    int gb = bbase[b];
    const uint* src = bdata + (size_t)b * MAXB;
    if (tid < 256) lcnt[tid] = 0;
    __syncthreads();
    for (int i = tid; i < ext; i += 1024) {
        uint v = src[i];
        if (v != SENT) atomicAdd(&lcnt[v >> 17], 1);
    }
    __syncthreads();
    if (tid < 256) lincl[tid] = lcnt[tid];
    __syncthreads();
    for (int d = 1; d < 256; d <<= 1) {
        int u = 0;
        if (tid < 256 && tid >= d) u = lincl[tid - d];
        __syncthreads();
        if (tid < 256) lincl[tid] += u;
        __syncthreads();
    }
    if (tid < 256) {
        int excl = lincl[tid] - lcnt[tid];
        lcur[tid] = excl;
        if (tid < nt) {
            offs[t0 + tid] = gb + excl;
            dinv[t0 + tid] = 1.0f / sqrtf((float)lcnt[tid] + 1.0f);  // +1 self loop
        }
    }
    if (b == 0 && tid == 0) offs[N] = E;
    __syncthreads();
    for (int i = tid; i < ext; i += 1024) {
        uint v = src[i];
        if (v != SENT) {
            int locc = v >> 17;
            int r = (int)(v & 0x1FFFFu);
            int pos = atomicAdd(&lcur[locc], 1);
            csr[gb + pos] = r;
        }
    }
}

// ---------------- weight prep: WT (blocks 0..255) + w2v (block 256) ----------------

__global__ __launch_bounds__(256) void prep_kernel(
        const float* __restrict__ W1, ushort* __restrict__ WT,
        const float* __restrict__ W2, const float* __restrict__ sw,
        float* __restrict__ w2v) {
    int bid = blockIdx.x;
    if (bid < 256) {
        int i = bid * 256 + threadIdx.x;     // i < 65536 = F_IN*F_H
        int k = i >> 7, c = i & 127;
        WT[c * F_IN + k] = f2bf(W1[i]);      // W_T[c][k] = bf16(W1[k][c])
    } else {
        int k = threadIdx.x;
        if (k < F_H) {
            float acc = 0.0f;
            #pragma unroll
            for (int c = 0; c < F_C; ++c) acc += W2[k * F_C + c] * sw[c];
            w2v[k] = acc;
        }
    }
}

// ---------------- GEMM1 via MFMA: H[N,128] (bf16) = (X @ W1) * dinv[row] ----------------
// block = 256 = 4 waves; tile 64 rows x 128 cols; wave w owns rows w*16..w*16+15, ALL cols.
// B[128 cols][64 k] staged per k-tile in LDS via global_load_lds with XOR-swizzled source.

__global__ __launch_bounds__(256) void gemm1_mfma(const float* __restrict__ X,
                                                  const ushort* __restrict__ WT,
                                                  const float* __restrict__ dinv,
                                                  ushort* __restrict__ H, int N) {
    __shared__ ushort Bl[128 * 64];   // 16 KB, [col][phys-chunk] 16B chunks, XOR-swizzled
    int tid = threadIdx.x;
    int w = tid >> 6, l = tid & 63;
    int r = l & 15, kg = l >> 4;
    int brow = blockIdx.x * 64 + w * 16;
    int row = brow + r; if (row >= N) row = N - 1;
    const float* xp = X + (size_t)row * F_IN + kg * 8;
    f32x4 acc[8] = {};

    for (int t = 0; t < 8; ++t) {
        int k0 = t * 64;
        float4 xa0 = *(const float4*)(xp + k0);
        float4 xa1 = *(const float4*)(xp + k0 + 4);
        float4 xb0 = *(const float4*)(xp + k0 + 32);
        float4 xb1 = *(const float4*)(xp + k0 + 36);
        __syncthreads();
        #pragma unroll
        for (int j = 0; j < 4; ++j) {
            int chunk = (w * 4 + j) * 64 + l;
            int col = chunk >> 3, ph = chunk & 7;
            const ushort* src = WT + (size_t)col * F_IN + k0 + ((ph ^ (col & 7)) << 3);
            gload_lds16(src, (char*)Bl + (size_t)(w * 4 + j) * 1024);
        }
        __syncthreads();
        union { short8 v; ushort u[8]; } A0, A1;
        A0.u[0] = f2bf(xa0.x); A0.u[1] = f2bf(xa0.y); A0.u[2] = f2bf(xa0.z); A0.u[3] = f2bf(xa0.w);
        A0.u[4] = f2bf(xa1.x); A0.u[5] = f2bf(xa1.y); A0.u[6] = f2bf(xa1.z); A0.u[7] = f2bf(xa1.w);
        A1.u[0] = f2bf(xb0.x); A1.u[1] = f2bf(xb0.y); A1.u[2] = f2bf(xb0.z); A1.u[3] = f2bf(xb0.w);
        A1.u[4] = f2bf(xb1.x); A1.u[5] = f2bf(xb1.y); A1.u[6] = f2bf(xb1.z); A1.u[7] = f2bf(xb1.w);
        #pragma unroll
        for (int f = 0; f < 8; ++f) {
            int col = f * 16 + r;
            short8 B0 = *(const short8*)((const char*)Bl + col * 128 + ((kg ^ (r & 7)) << 4));
            acc[f] = __builtin_amdgcn_mfma_f32_16x16x32_bf16(A0.v, B0, acc[f], 0, 0, 0);
        }
        #pragma unroll
        for (int f = 0; f < 8; ++f) {
            int col = f * 16 + r;
            short8 B1 = *(const short8*)((const char*)Bl + col * 128 + (((4 + kg) ^ (r & 7)) << 4));
            acc[f] = __builtin_amdgcn_mfma_f32_16x16x32_bf16(A1.v, B1, acc[f], 0, 0, 0);
        }
    }
    // D: col = lane&15, row = (lane>>4)*4 + reg; scale by dinv[row] on store
    float dv[4];
    #pragma unroll
    for (int rr = 0; rr < 4; ++rr) {
        int orow = brow + kg * 4 + rr;
        dv[rr] = (orow < N) ? dinv[orow] : 0.0f;
    }
    #pragma unroll
    for (int f = 0; f < 8; ++f) {
        #pragma unroll
        for (int rr = 0; rr < 4; ++rr) {
            int orow = brow + kg * 4 + rr;
            if (orow < N) H[(size_t)orow * F_H + f * 16 + r] = f2bf(acc[f][rr] * dv[rr]);
        }
    }
}

// ---------------- agg1 + relu + dot(w2v) -> gs ----------------
// one wave per node; 16 lanes per edge (lane loads uint4 = 8 bf16 of the 256B row);
// 8 edges per quarter-wave iteration = 32 edges/iter, 8 gathers in flight per wave.

#define ACC4(U) \
    acc[0] += bflo(U.x); acc[1] += bfhi(U.x); acc[2] += bflo(U.y); acc[3] += bfhi(U.y); \
    acc[4] += bflo(U.z); acc[5] += bfhi(U.z); acc[6] += bflo(U.w); acc[7] += bfhi(U.w);

__global__ __launch_bounds__(256) void agg1_g_kernel(
        const ushort* __restrict__ H, const int* __restrict__ offs,
        const int* __restrict__ csr, const float* __restrict__ dinv,
        const float* __restrict__ b1, const float* __restrict__ w2v,
        float* __restrict__ gs, int N) {
    int gw = (int)((blockIdx.x * blockDim.x + threadIdx.x) >> 6);
    if (gw >= N) return;
    int lane = threadIdx.x & 63;
    int q = lane >> 4, fr = lane & 15;
    size_t fb = (size_t)fr * 16;
    float acc[8] = {};
    if (q == 0) {                          // self term
        uint4 u = *(const uint4*)((const char*)H + (size_t)gw * 256 + fb);
        ACC4(u);
    }
    int s = offs[gw], e = offs[gw + 1];
    int i = s;
    // 32 edges/iter: 8 idx loads then 8 independent gathers in flight
    for (; i + 32 <= e; i += 32) {
        int idx[8];
        #pragma unroll
        for (int k = 0; k < 8; ++k) idx[k] = csr[i + 4 * k + q];
        uint4 u[8];
        #pragma unroll
        for (int k = 0; k < 8; ++k)
            u[k] = *(const uint4*)((const char*)H + (size_t)idx[k] * 256 + fb);
        #pragma unroll
        for (int k = 0; k < 8; ++k) { ACC4(u[k]); }
    }
    for (; i + 8 <= e; i += 8) {
        int i0 = csr[i + q], i1 = csr[i + 4 + q];
        uint4 u0 = *(const uint4*)((const char*)H + (size_t)i0 * 256 + fb);
        uint4 u1 = *(const uint4*)((const char*)H + (size_t)i1 * 256 + fb);
        ACC4(u0); ACC4(u1);
    }
    for (; i + 4 <= e; i += 4) {
        int i0 = csr[i + q];
        uint4 u0 = *(const uint4*)((const char*)H + (size_t)i0 * 256 + fb);
        ACC4(u0);
    }
    if (q < e - i) {
        int i0 = csr[i + q];
        uint4 u0 = *(const uint4*)((const char*)H + (size_t)i0 * 256 + fb);
        ACC4(u0);
    }
    #pragma unroll
    for (int f = 0; f < 8; ++f) {
        acc[f] += __shfl_xor(acc[f], 16, 64);
        acc[f] += __shfl_xor(acc[f], 32, 64);
    }
    float di = dinv[gw];
    float4 bv0 = *(const float4*)(b1 + fr * 8);
    float4 bv1 = *(const float4*)(b1 + fr * 8 + 4);
    float4 wv0 = *(const float4*)(w2v + fr * 8);
    float4 wv1 = *(const float4*)(w2v + fr * 8 + 4);
    float v = fmaxf(fmaf(di, acc[0], bv0.x), 0.0f) * wv0.x;
    v = fmaf(fmaxf(fmaf(di, acc[1], bv0.y), 0.0f), wv0.y, v);
    v = fmaf(fmaxf(fmaf(di, acc[2], bv0.z), 0.0f), wv0.z, v);
    v = fmaf(fmaxf(fmaf(di, acc[3], bv0.w), 0.0f), wv0.w, v);
    v = fmaf(fmaxf(fmaf(di, acc[4], bv1.x), 0.0f), wv1.x, v);
    v = fmaf(fmaxf(fmaf(di, acc[5], bv1.y), 0.0f), wv1.y, v);
    v = fmaf(fmaxf(fmaf(di, acc[6], bv1.z), 0.0f), wv1.z, v);
    v = fmaf(fmaxf(fmaf(di, acc[7], bv1.w), 0.0f), wv1.w, v);
    v += __shfl_xor(v, 1, 64);
    v += __shfl_xor(v, 2, 64);
    v += __shfl_xor(v, 4, 64);
    v += __shfl_xor(v, 8, 64);
    if (lane == 0) gs[gw] = v * di;       // pre-scaled for layer-2 agg
}

// ---------------- scalar aggregation: hw[c] = dinv[c] * (gs[c] + sum gs[src]) ----------
// gs is 400KB -> L2-resident; 16 independent gathers in flight per thread.

__global__ void agg_s_kernel(const float* __restrict__ gs, const int* __restrict__ offs,
                             const int* __restrict__ csr, const float* __restrict__ dinv,
                             float* __restrict__ hw, int N) {
    int i = blockIdx.x * blockDim.x + threadIdx.x;
    if (i >= N) return;
    float acc = gs[i];
    int s = offs[i], e = offs[i + 1];
    int j = s;
    for (; j + 16 <= e; j += 16) {
        int idx[16];
        #pragma unroll
        for (int k = 0; k < 16; ++k) idx[k] = csr[j + k];
        float g[16];
        #pragma unroll
        for (int k = 0; k < 16; ++k) g[k] = gs[idx[k]];
        float t0 = ((g[0] + g[1]) + (g[2] + g[3])) + ((g[4] + g[5]) + (g[6] + g[7]));
        float t1 = ((g[8] + g[9]) + (g[10] + g[11])) + ((g[12] + g[13]) + (g[14] + g[15]));
        acc += t0 + t1;
    }
    for (; j + 4 <= e; j += 4) {
        int s0 = csr[j], s1 = csr[j+1], s2 = csr[j+2], s3 = csr[j+3];
        acc += (gs[s0] + gs[s1]) + (gs[s2] + gs[s3]);
    }
    for (; j < e; ++j) acc += gs[csr[j]];
    hw[i] = acc * dinv[i];
}

// ---------------- per-edge scoring ----------------

__global__ __launch_bounds__(256) void score_kernel(
        const float* __restrict__ hw, const int* __restrict__ pos_ei,
        const int* __restrict__ neg_ei, int Ep, const float* __restrict__ score_b,
        float* __restrict__ out, float* __restrict__ partials) {
    __shared__ float sdata[256];
    int Etot = 2 * Ep;
    int idx = blockIdx.x * 256 + threadIdx.x;
    float local = 0.0f;
    if (idx < Etot) {
        int src, dst;
        if (idx < Ep) { src = pos_ei[idx];       dst = pos_ei[Ep + idx]; }
        else          { int e = idx - Ep; src = neg_ei[e]; dst = neg_ei[Ep + e]; }
        float s = hw[src] - hw[dst];
        out[idx] = fmaxf(s + score_b[0], 0.0f);
        local = s;
    }
    sdata[threadIdx.x] = local;
    __syncthreads();
    for (int d = 128; d; d >>= 1) {
        if ((int)threadIdx.x < d) sdata[threadIdx.x] += sdata[threadIdx.x + d];
        __syncthreads();
    }
    if (threadIdx.x == 0) partials[blockIdx.x] = sdata[0];
}

__global__ void loss_final_kernel(const float* __restrict__ partials, int n,
                                  float* __restrict__ loss_out, float inv) {
    __shared__ float sdata[256];
    float local = 0.0f;
    for (int i = threadIdx.x; i < n; i += 256) local += partials[i];
    sdata[threadIdx.x] = local;
    __syncthreads();
    for (int d = 128; d; d >>= 1) {
        if ((int)threadIdx.x < d) sdata[threadIdx.x] += sdata[threadIdx.x + d];
        __syncthreads();
    }
    if (threadIdx.x == 0) *loss_out = sdata[0] * inv;
}

// ---------------- launch ----------------

extern "C" void kernel_launch(void* const* d_in, const int* in_sizes, int n_in,
                              void* d_out, int out_size, void* d_ws, size_t ws_size,
                              hipStream_t stream) {
    const float* x        = (const float*)d_in[0];
    const int*   edge     = (const int*)d_in[1];
    const int*   pos_ei   = (const int*)d_in[2];
    const int*   neg_ei   = (const int*)d_in[3];
    const float* W1       = (const float*)d_in[4];
    const float* b1       = (const float*)d_in[5];
    const float* W2       = (const float*)d_in[6];
    const float* score_w  = (const float*)d_in[8];
    const float* score_b  = (const float*)d_in[9];

    int N    = in_sizes[0] / F_IN;   // 100000
    int E    = in_sizes[1] / 2;      // 3.2M
    int Ep   = in_sizes[2] / 2;      // 500k
    int Etot = 2 * Ep;               // 1M
    float* out = (float*)d_out;      // [Etot] scores then [1] loss

    int NB = (N + 255) >> 8;         // 391 buckets
    int ntiles = (E + 4095) >> 12;   // 782 tiles of 4096 edges

    // workspace carve (256B aligned), ~40 MB total
    char* p = (char*)d_ws;
    auto alloc = [&](size_t bytes) { char* r = p; p += (bytes + 255) & ~(size_t)255; return r; };
    int*    offs     = (int*)   alloc((size_t)(N + 1) * 4);
    int*    bcr      = (int*)   alloc((size_t)2 * NBMAX * 4);   // bcnt | rcnt
    int*    bcnt     = bcr;
    int*    rcnt     = bcr + NBMAX;
    int*    bbase    = (int*)   alloc((size_t)(NBMAX + 1) * 4);
    float*  dinv     = (float*) alloc((size_t)N * 4);
    float*  gsb      = (float*) alloc((size_t)N * 4);
    float*  hw       = (float*) alloc((size_t)N * 4);
    float*  w2v      = (float*) alloc(F_H * 4);
    ushort* WT       = (ushort*)alloc((size_t)F_IN * F_H * 2);
    int*    csr      = (int*)   alloc((size_t)E * 4);
    // bdata (NB*MAXB*4 = 22.4MB) overlaid with h1 (N*128*2 = 25.6MB):
    // bdata fully consumed by bucketB before gemm1 writes h1.
    size_t big = (size_t)NBMAX * MAXB * 4;
    size_t h1b = (size_t)N * F_H * 2;
    char*   bigbuf   = (char*)  alloc(big > h1b ? big : h1b);
    uint*   bdata    = (uint*)bigbuf;
    ushort* h1       = (ushort*)bigbuf;
    int sblk = (Etot + 255) / 256;
    float*  partials = (float*) alloc((size_t)sblk * 4);

    hipMemsetAsync(bcr, 0, (size_t)2 * NBMAX * 4, stream);
    bucketA_kernel<<<128, 1024, 0, stream>>>(edge, E, ntiles, NB, bdata, bcnt, rcnt);
    bbase_kernel<<<1, 512, 0, stream>>>(rcnt, bbase, NB, E);
    bucketB_kernel<<<NB, 1024, 0, stream>>>(bdata, bcnt, bbase, csr, offs, dinv, N, E);
    prep_kernel<<<257, 256, 0, stream>>>(W1, WT, W2, score_w, w2v);
    gemm1_mfma<<<(N + 63) / 64, 256, 0, stream>>>(x, WT, dinv, h1, N);
    agg1_g_kernel<<<(N * 64 + 255) / 256, 256, 0, stream>>>(h1, offs, csr, dinv, b1,
                                                            w2v, gsb, N);
    agg_s_kernel<<<(N + 255) / 256, 256, 0, stream>>>(gsb, offs, csr, dinv, hw, N);
    score_kernel<<<sblk, 256, 0, stream>>>(hw, pos_ei, neg_ei, Ep, score_b, out, partials);
    loss_final_kernel<<<1, 256, 0, stream>>>(partials, sblk, out + Etot, 1.0f / (float)Etot);
}

// Round 9
// 541.069 us; speedup vs baseline: 1.0373x; 1.0373x over previous
//
#include <hip/hip_runtime.h>
#include <hip/hip_bf16.h>

// GCN link-prediction net, algebraically collapsed + dinv pre-scaling:
//   H[r]  = bf16( (x @ W1)[r] * dinv[r] )            (bf16 MFMA, fp32 accum)
//   agg1[c] = dinv[c] * ( H[c] + sum_{e->c} H[src] ) (unweighted sum)
//   g[c]  = relu(agg1[c] + b1) . (W2 @ score_w);  gs[c] = g[c]*dinv[c]
//   hw[c] = dinv[c] * ( gs[c] + sum gs[src] )
//   out[e] = relu(hw[src]-hw[dst] + sb); loss = mean(hw[src]-hw[dst])
// CSR via two-phase bucket sort with LDS write-combining (R7: 906->555us).
// R9: bucketA grid 128->256 (was using half the CUs); gemm1 128-row blocks
// (8 waves) halving B re-staging traffic (was 200MB = the whole X read).

#define F_IN 512
#define F_H  128
#define F_C  64

#define NBMAX 392          // buckets of 256 targets, N=100000 -> 391
#define MAXB  14336        // padded per-bucket capacity (mean 12.9k + >10 sigma)
#define SENT  0xFFFFFFFFu

typedef __attribute__((ext_vector_type(8))) short short8;
typedef __attribute__((ext_vector_type(4))) float f32x4;

__device__ __forceinline__ ushort f2bf(float f) {
    uint u = __float_as_uint(f);
    uint r = (u + 0x7fffu + ((u >> 16) & 1u)) >> 16;   // RNE
    return (ushort)r;
}
__device__ __forceinline__ float bflo(uint v) { return __uint_as_float(v << 16); }
__device__ __forceinline__ float bfhi(uint v) { return __uint_as_float(v & 0xffff0000u); }

__device__ __forceinline__ void gload_lds16(const void* g, void* l) {
    __builtin_amdgcn_global_load_lds(
        (const __attribute__((address_space(1))) void*)g,
        (__attribute__((address_space(3))) void*)l, 16, 0, 0);
}

// ---------------- phase A: bucket edges with line-aligned flushes ----------------

__global__ __launch_bounds__(1024) void bucketA_kernel(
        const int* __restrict__ ei, int E, int ntiles, int NB,
        uint* __restrict__ bdata, int* __restrict__ bcnt, int* __restrict__ rcnt) {
    __shared__ int  hist[512];
    __shared__ uint stage[NBMAX * 32];
    int tid = threadIdx.x;
    if (tid < NB) hist[tid] = 0;
    __syncthreads();
    for (int tb = blockIdx.x; tb < ntiles; tb += gridDim.x) {
        int e0 = tb * 4096;
        #pragma unroll
        for (int j = 0; j < 4; ++j) {
            int e = e0 + j * 1024 + tid;
            if (e < E) {
                int r = ei[e];              // source
                int c = ei[E + e];          // target
                int b = c >> 8;
                uint pk = ((uint)(c & 255) << 17) | (uint)r;
                int pos = atomicAdd(&hist[b], 1);
                if (pos < 32) {
                    stage[b * 32 + pos] = pk;
                } else {                    // overflow (P ~ 1e-5): padded line
                    int gp = atomicAdd(&bcnt[b], 16);
                    atomicAdd(&rcnt[b], 1);
                    uint4* dst = (uint4*)(bdata + (size_t)b * MAXB + gp);
                    uint4 v0 = {pk, SENT, SENT, SENT};
                    uint4 vs = {SENT, SENT, SENT, SENT};
                    dst[0] = v0; dst[1] = vs; dst[2] = vs; dst[3] = vs;
                }
            }
        }
        __syncthreads();
        if (tid < NB) {
            int h = hist[tid];
            int st = h < 32 ? h : 32;
            if (st > 0) {
                int pads = (st + 15) & ~15;
                int gp = atomicAdd(&bcnt[tid], pads);
                atomicAdd(&rcnt[tid], st);
                uint* dst = bdata + (size_t)tid * MAXB + gp;
                for (int k = 0; k < pads; k += 4) {
                    uint4 v;
                    v.x = (k + 0 < st) ? stage[tid * 32 + k + 0] : SENT;
                    v.y = (k + 1 < st) ? stage[tid * 32 + k + 1] : SENT;
                    v.z = (k + 2 < st) ? stage[tid * 32 + k + 2] : SENT;
                    v.w = (k + 3 < st) ? stage[tid * 32 + k + 3] : SENT;
                    *(uint4*)(dst + k) = v;
                }
            }
            hist[tid] = 0;
        }
        __syncthreads();
    }
}

// exclusive scan of real bucket counts -> bbase[0..NB], bbase[NB]=E
__global__ __launch_bounds__(512) void bbase_kernel(const int* __restrict__ rcnt,
                                                    int* __restrict__ bbase,
                                                    int NB, int E) {
    __shared__ int sm[512];
    int t = threadIdx.x;
    int v = (t < NB) ? rcnt[t] : 0;
    sm[t] = v;
    __syncthreads();
    for (int d = 1; d < 512; d <<= 1) {
        int u = (t >= d) ? sm[t - d] : 0;
        __syncthreads();
        sm[t] += u;
        __syncthreads();
    }
    if (t < NB) bbase[t] = sm[t] - v;
    if (t == 0) bbase[NB] = E;
}

// ---------------- phase B: per-bucket counting sort -> csr, offs, dinv ----------------

__global__ __launch_bounds__(1024) void bucketB_kernel(
        const uint* __restrict__ bdata, const int* __restrict__ bcnt,
        const int* __restrict__ bbase, int* __restrict__ csr,
        int* __restrict__ offs, float* __restrict__ dinv, int N, int E) {
    __shared__ int lcnt[256], lincl[256], lcur[256];
    int b = blockIdx.x, tid = threadIdx.x;
    int t0 = b << 8;
    int nt = N - t0; if (nt > 256) nt = 256;
    int ext = bcnt[b];
    int gb = bbase[b];
    const uint* src = bdata + (size_t)b * MAXB;
    if (tid < 256) lcnt[tid] = 0;
    __syncthreads();
    for (int i = tid; i < ext; i += 1024) {
        uint v = src[i];
        if (v != SENT) atomicAdd(&lcnt[v >> 17], 1);
    }
    __syncthreads();
    if (tid < 256) lincl[tid] = lcnt[tid];
    __syncthreads();
    for (int d = 1; d < 256; d <<= 1) {
        int u = 0;
        if (tid < 256 && tid >= d) u = lincl[tid - d];
        __syncthreads();
        if (tid < 256) lincl[tid] += u;
        __syncthreads();
    }
    if (tid < 256) {
        int excl = lincl[tid] - lcnt[tid];
        lcur[tid] = excl;
        if (tid < nt) {
            offs[t0 + tid] = gb + excl;
            dinv[t0 + tid] = 1.0f / sqrtf((float)lcnt[tid] + 1.0f);  // +1 self loop
        }
    }
    if (b == 0 && tid == 0) offs[N] = E;
    __syncthreads();
    for (int i = tid; i < ext; i += 1024) {
        uint v = src[i];
        if (v != SENT) {
            int locc = v >> 17;
            int r = (int)(v & 0x1FFFFu);
            int pos = atomicAdd(&lcur[locc], 1);
            csr[gb + pos] = r;
        }
    }
}

// ---------------- weight prep: WT (blocks 0..255) + w2v (block 256) ----------------

__global__ __launch_bounds__(256) void prep_kernel(
        const float* __restrict__ W1, ushort* __restrict__ WT,
        const float* __restrict__ W2, const float* __restrict__ sw,
        float* __restrict__ w2v) {
    int bid = blockIdx.x;
    if (bid < 256) {
        int i = bid * 256 + threadIdx.x;     // i < 65536 = F_IN*F_H
        int k = i >> 7, c = i & 127;
        WT[c * F_IN + k] = f2bf(W1[i]);      // W_T[c][k] = bf16(W1[k][c])
    } else {
        int k = threadIdx.x;
        if (k < F_H) {
            float acc = 0.0f;
            #pragma unroll
            for (int c = 0; c < F_C; ++c) acc += W2[k * F_C + c] * sw[c];
            w2v[k] = acc;
        }
    }
}

// ---------------- GEMM1 via MFMA: H[N,128] (bf16) = (X @ W1) * dinv[row] ----------------
// block = 512 = 8 waves; tile 128 rows x 128 cols; wave w owns rows w*16..w*16+15,
// ALL cols. B[128 cols][64 k] staged per k-tile via global_load_lds, XOR-swizzled src.

__global__ __launch_bounds__(512) void gemm1_mfma(const float* __restrict__ X,
                                                  const ushort* __restrict__ WT,
                                                  const float* __restrict__ dinv,
                                                  ushort* __restrict__ H, int N) {
    __shared__ ushort Bl[128 * 64];   // 16 KB, [col][phys-chunk] 16B chunks, XOR-swizzled
    int tid = threadIdx.x;
    int w = tid >> 6, l = tid & 63;
    int r = l & 15, kg = l >> 4;
    int brow = blockIdx.x * 128 + w * 16;
    int row = brow + r; if (row >= N) row = N - 1;
    const float* xp = X + (size_t)row * F_IN + kg * 8;
    f32x4 acc[8] = {};

    for (int t = 0; t < 8; ++t) {
        int k0 = t * 64;
        float4 xa0 = *(const float4*)(xp + k0);
        float4 xa1 = *(const float4*)(xp + k0 + 4);
        float4 xb0 = *(const float4*)(xp + k0 + 32);
        float4 xb1 = *(const float4*)(xp + k0 + 36);
        __syncthreads();
        // stage B tile: 1024 chunks of 16B; wave w stages chunks (w*2+j)*64 + l
        #pragma unroll
        for (int j = 0; j < 2; ++j) {
            int chunk = (w * 2 + j) * 64 + l;
            int col = chunk >> 3, ph = chunk & 7;
            const ushort* src = WT + (size_t)col * F_IN + k0 + ((ph ^ (col & 7)) << 3);
            gload_lds16(src, (char*)Bl + (size_t)(w * 2 + j) * 1024);
        }
        __syncthreads();
        union { short8 v; ushort u[8]; } A0, A1;
        A0.u[0] = f2bf(xa0.x); A0.u[1] = f2bf(xa0.y); A0.u[2] = f2bf(xa0.z); A0.u[3] = f2bf(xa0.w);
        A0.u[4] = f2bf(xa1.x); A0.u[5] = f2bf(xa1.y); A0.u[6] = f2bf(xa1.z); A0.u[7] = f2bf(xa1.w);
        A1.u[0] = f2bf(xb0.x); A1.u[1] = f2bf(xb0.y); A1.u[2] = f2bf(xb0.z); A1.u[3] = f2bf(xb0.w);
        A1.u[4] = f2bf(xb1.x); A1.u[5] = f2bf(xb1.y); A1.u[6] = f2bf(xb1.z); A1.u[7] = f2bf(xb1.w);
        #pragma unroll
        for (int f = 0; f < 8; ++f) {
            int col = f * 16 + r;
            short8 B0 = *(const short8*)((const char*)Bl + col * 128 + ((kg ^ (r & 7)) << 4));
            acc[f] = __builtin_amdgcn_mfma_f32_16x16x32_bf16(A0.v, B0, acc[f], 0, 0, 0);
        }
        #pragma unroll
        for (int f = 0; f < 8; ++f) {
            int col = f * 16 + r;
            short8 B1 = *(const short8*)((const char*)Bl + col * 128 + (((4 + kg) ^ (r & 7)) << 4));
            acc[f] = __builtin_amdgcn_mfma_f32_16x16x32_bf16(A1.v, B1, acc[f], 0, 0, 0);
        }
    }
    // D: col = lane&15, row = (lane>>4)*4 + reg; scale by dinv[row] on store
    float dv[4];
    #pragma unroll
    for (int rr = 0; rr < 4; ++rr) {
        int orow = brow + kg * 4 + rr;
        dv[rr] = (orow < N) ? dinv[orow] : 0.0f;
    }
    #pragma unroll
    for (int f = 0; f < 8; ++f) {
        #pragma unroll
        for (int rr = 0; rr < 4; ++rr) {
            int orow = brow + kg * 4 + rr;
            if (orow < N) H[(size_t)orow * F_H + f * 16 + r] = f2bf(acc[f][rr] * dv[rr]);
        }
    }
}

// ---------------- agg1 + relu + dot(w2v) -> gs ----------------
// one wave per node; 16 lanes per edge (lane loads uint4 = 8 bf16 of the 256B row);
// 8 edges per quarter-wave iteration = 32 edges/iter, 8 gathers in flight per wave.

#define ACC4(U) \
    acc[0] += bflo(U.x); acc[1] += bfhi(U.x); acc[2] += bflo(U.y); acc[3] += bfhi(U.y); \
    acc[4] += bflo(U.z); acc[5] += bfhi(U.z); acc[6] += bflo(U.w); acc[7] += bfhi(U.w);

__global__ __launch_bounds__(256) void agg1_g_kernel(
        const ushort* __restrict__ H, const int* __restrict__ offs,
        const int* __restrict__ csr, const float* __restrict__ dinv,
        const float* __restrict__ b1, const float* __restrict__ w2v,
        float* __restrict__ gs, int N) {
    int gw = (int)((blockIdx.x * blockDim.x + threadIdx.x) >> 6);
    if (gw >= N) return;
    int lane = threadIdx.x & 63;
    int q = lane >> 4, fr = lane & 15;
    size_t fb = (size_t)fr * 16;
    float acc[8] = {};
    if (q == 0) {                          // self term
        uint4 u = *(const uint4*)((const char*)H + (size_t)gw * 256 + fb);
        ACC4(u);
    }
    int s = offs[gw], e = offs[gw + 1];
    int i = s;
    for (; i + 32 <= e; i += 32) {
        int idx[8];
        #pragma unroll
        for (int k = 0; k < 8; ++k) idx[k] = csr[i + 4 * k + q];
        uint4 u[8];
        #pragma unroll
        for (int k = 0; k < 8; ++k)
            u[k] = *(const uint4*)((const char*)H + (size_t)idx[k] * 256 + fb);
        #pragma unroll
        for (int k = 0; k < 8; ++k) { ACC4(u[k]); }
    }
    for (; i + 8 <= e; i += 8) {
        int i0 = csr[i + q], i1 = csr[i + 4 + q];
        uint4 u0 = *(const uint4*)((const char*)H + (size_t)i0 * 256 + fb);
        uint4 u1 = *(const uint4*)((const char*)H + (size_t)i1 * 256 + fb);
        ACC4(u0); ACC4(u1);
    }
    for (; i + 4 <= e; i += 4) {
        int i0 = csr[i + q];
        uint4 u0 = *(const uint4*)((const char*)H + (size_t)i0 * 256 + fb);
        ACC4(u0);
    }
    if (q < e - i) {
        int i0 = csr[i + q];
        uint4 u0 = *(const uint4*)((const char*)H + (size_t)i0 * 256 + fb);
        ACC4(u0);
    }
    #pragma unroll
    for (int f = 0; f < 8; ++f) {
        acc[f] += __shfl_xor(acc[f], 16, 64);
        acc[f] += __shfl_xor(acc[f], 32, 64);
    }
    float di = dinv[gw];
    float4 bv0 = *(const float4*)(b1 + fr * 8);
    float4 bv1 = *(const float4*)(b1 + fr * 8 + 4);
    float4 wv0 = *(const float4*)(w2v + fr * 8);
    float4 wv1 = *(const float4*)(w2v + fr * 8 + 4);
    float v = fmaxf(fmaf(di, acc[0], bv0.x), 0.0f) * wv0.x;
    v = fmaf(fmaxf(fmaf(di, acc[1], bv0.y), 0.0f), wv0.y, v);
    v = fmaf(fmaxf(fmaf(di, acc[2], bv0.z), 0.0f), wv0.z, v);
    v = fmaf(fmaxf(fmaf(di, acc[3], bv0.w), 0.0f), wv0.w, v);
    v = fmaf(fmaxf(fmaf(di, acc[4], bv1.x), 0.0f), wv1.x, v);
    v = fmaf(fmaxf(fmaf(di, acc[5], bv1.y), 0.0f), wv1.y, v);
    v = fmaf(fmaxf(fmaf(di, acc[6], bv1.z), 0.0f), wv1.z, v);
    v = fmaf(fmaxf(fmaf(di, acc[7], bv1.w), 0.0f), wv1.w, v);
    v += __shfl_xor(v, 1, 64);
    v += __shfl_xor(v, 2, 64);
    v += __shfl_xor(v, 4, 64);
    v += __shfl_xor(v, 8, 64);
    if (lane == 0) gs[gw] = v * di;       // pre-scaled for layer-2 agg
}

// ---------------- scalar aggregation: hw[c] = dinv[c] * (gs[c] + sum gs[src]) ----------

__global__ void agg_s_kernel(const float* __restrict__ gs, const int* __restrict__ offs,
                             const int* __restrict__ csr, const float* __restrict__ dinv,
                             float* __restrict__ hw, int N) {
    int i = blockIdx.x * blockDim.x + threadIdx.x;
    if (i >= N) return;
    float acc = gs[i];
    int s = offs[i], e = offs[i + 1];
    int j = s;
    for (; j + 16 <= e; j += 16) {
        int idx[16];
        #pragma unroll
        for (int k = 0; k < 16; ++k) idx[k] = csr[j + k];
        float g[16];
        #pragma unroll
        for (int k = 0; k < 16; ++k) g[k] = gs[idx[k]];
        float t0 = ((g[0] + g[1]) + (g[2] + g[3])) + ((g[4] + g[5]) + (g[6] + g[7]));
        float t1 = ((g[8] + g[9]) + (g[10] + g[11])) + ((g[12] + g[13]) + (g[14] + g[15]));
        acc += t0 + t1;
    }
    for (; j + 4 <= e; j += 4) {
        int s0 = csr[j], s1 = csr[j+1], s2 = csr[j+2], s3 = csr[j+3];
        acc += (gs[s0] + gs[s1]) + (gs[s2] + gs[s3]);
    }
    for (; j < e; ++j) acc += gs[csr[j]];
    hw[i] = acc * dinv[i];
}

// ---------------- per-edge scoring ----------------

__global__ __launch_bounds__(256) void score_kernel(
        const float* __restrict__ hw, const int* __restrict__ pos_ei,
        const int* __restrict__ neg_ei, int Ep, const float* __restrict__ score_b,
        float* __restrict__ out, float* __restrict__ partials) {
    __shared__ float sdata[256];
    int Etot = 2 * Ep;
    int idx = blockIdx.x * 256 + threadIdx.x;
    float local = 0.0f;
    if (idx < Etot) {
        int src, dst;
        if (idx < Ep) { src = pos_ei[idx];       dst = pos_ei[Ep + idx]; }
        else          { int e = idx - Ep; src = neg_ei[e]; dst = neg_ei[Ep + e]; }
        float s = hw[src] - hw[dst];
        out[idx] = fmaxf(s + score_b[0], 0.0f);
        local = s;
    }
    sdata[threadIdx.x] = local;
    __syncthreads();
    for (int d = 128; d; d >>= 1) {
        if ((int)threadIdx.x < d) sdata[threadIdx.x] += sdata[threadIdx.x + d];
        __syncthreads();
    }
    if (threadIdx.x == 0) partials[blockIdx.x] = sdata[0];
}

__global__ void loss_final_kernel(const float* __restrict__ partials, int n,
                                  float* __restrict__ loss_out, float inv) {
    __shared__ float sdata[256];
    float local = 0.0f;
    for (int i = threadIdx.x; i < n; i += 256) local += partials[i];
    sdata[threadIdx.x] = local;
    __syncthreads();
    for (int d = 128; d; d >>= 1) {
        if ((int)threadIdx.x < d) sdata[threadIdx.x] += sdata[threadIdx.x + d];
        __syncthreads();
    }
    if (threadIdx.x == 0) *loss_out = sdata[0] * inv;
}

// ---------------- launch ----------------

extern "C" void kernel_launch(void* const* d_in, const int* in_sizes, int n_in,
                              void* d_out, int out_size, void* d_ws, size_t ws_size,
                              hipStream_t stream) {
    const float* x        = (const float*)d_in[0];
    const int*   edge     = (const int*)d_in[1];
    const int*   pos_ei   = (const int*)d_in[2];
    const int*   neg_ei   = (const int*)d_in[3];
    const float* W1       = (const float*)d_in[4];
    const float* b1       = (const float*)d_in[5];
    const float* W2       = (const float*)d_in[6];
    const float* score_w  = (const float*)d_in[8];
    const float* score_b  = (const float*)d_in[9];

    int N    = in_sizes[0] / F_IN;   // 100000
    int E    = in_sizes[1] / 2;      // 3.2M
    int Ep   = in_sizes[2] / 2;      // 500k
    int Etot = 2 * Ep;               // 1M
    float* out = (float*)d_out;      // [Etot] scores then [1] loss

    int NB = (N + 255) >> 8;         // 391 buckets
    int ntiles = (E + 4095) >> 12;   // 782 tiles of 4096 edges

    // workspace carve (256B aligned), ~40 MB total
    char* p = (char*)d_ws;
    auto alloc = [&](size_t bytes) { char* r = p; p += (bytes + 255) & ~(size_t)255; return r; };
    int*    offs     = (int*)   alloc((size_t)(N + 1) * 4);
    int*    bcr      = (int*)   alloc((size_t)2 * NBMAX * 4);   // bcnt | rcnt
    int*    bcnt     = bcr;
    int*    rcnt     = bcr + NBMAX;
    int*    bbase    = (int*)   alloc((size_t)(NBMAX + 1) * 4);
    float*  dinv     = (float*) alloc((size_t)N * 4);
    float*  gsb      = (float*) alloc((size_t)N * 4);
    float*  hw       = (float*) alloc((size_t)N * 4);
    float*  w2v      = (float*) alloc(F_H * 4);
    ushort* WT       = (ushort*)alloc((size_t)F_IN * F_H * 2);
    int*    csr      = (int*)   alloc((size_t)E * 4);
    // bdata (22.4MB) overlaid with h1 (25.6MB): bdata consumed before gemm1.
    size_t big = (size_t)NBMAX * MAXB * 4;
    size_t h1b = (size_t)N * F_H * 2;
    char*   bigbuf   = (char*)  alloc(big > h1b ? big : h1b);
    uint*   bdata    = (uint*)bigbuf;
    ushort* h1       = (ushort*)bigbuf;
    int sblk = (Etot + 255) / 256;
    float*  partials = (float*) alloc((size_t)sblk * 4);

    hipMemsetAsync(bcr, 0, (size_t)2 * NBMAX * 4, stream);
    bucketA_kernel<<<256, 1024, 0, stream>>>(edge, E, ntiles, NB, bdata, bcnt, rcnt);
    bbase_kernel<<<1, 512, 0, stream>>>(rcnt, bbase, NB, E);
    bucketB_kernel<<<NB, 1024, 0, stream>>>(bdata, bcnt, bbase, csr, offs, dinv, N, E);
    prep_kernel<<<257, 256, 0, stream>>>(W1, WT, W2, score_w, w2v);
    gemm1_mfma<<<(N + 127) / 128, 512, 0, stream>>>(x, WT, dinv, h1, N);
    agg1_g_kernel<<<(N * 64 + 255) / 256, 256, 0, stream>>>(h1, offs, csr, dinv, b1,
                                                            w2v, gsb, N);
    agg_s_kernel<<<(N + 255) / 256, 256, 0, stream>>>(gsb, offs, csr, dinv, hw, N);
    score_kernel<<<sblk, 256, 0, stream>>>(hw, pos_ei, neg_ei, Ep, score_b, out, partials);
    loss_final_kernel<<<1, 256, 0, stream>>>(partials, sblk, out + Etot, 1.0f / (float)Etot);
}